// Round 5
// baseline (218.074 us; speedup 1.0000x reference)
//
#include <hip/hip_runtime.h>

// Problem: N=65536 rows, C=100 classes, 6 matrices (outputs1..5, mimic).
// out[0]            = max over ALL elements of outputs1..5
// out[1 + row*6 + j]= softmax_j(margins(row)/TEMP), TEMP=2
// margin(x,t) = (x[t] == max(x)) ? max(x) - second_max(x) : 0
//
// R4 post-mortem: thread-per-row = 256 blocks = 1 block/CU -> occupancy 10%,
// latency-bound at 1.1 TB/s. This version: 2D grid (row-block, matrix),
// 6x65536 threads = 24 waves/CU. Kernel 1 writes raw margins into out[];
// kernel 2 does the 6-wide softmax in-place + final max decode.

constexpr int C = 100;            // classes per row (25 float4)
constexpr float INV_TEMP = 0.5f;  // 1/TEMP

// Order-preserving float -> unsigned encoding (for atomicMax on any-sign floats)
__device__ __forceinline__ unsigned enc_f(float f) {
    unsigned u = __float_as_uint(f);
    return (u & 0x80000000u) ? ~u : (u | 0x80000000u);
}

// ws[0] = encoded running max; init to encoded -inf (0x007FFFFF).
__global__ void setup_kernel(unsigned* __restrict__ ws) {
    ws[0] = 0x007FFFFFu;
}

// Grid: (ceil(n/256), 6). One thread per (row, matrix).
__global__ __launch_bounds__(256) void margin_kernel(
    const float* __restrict__ o1, const float* __restrict__ o2,
    const float* __restrict__ o3, const float* __restrict__ o4,
    const float* __restrict__ o5, const float* __restrict__ mimic,
    const int* __restrict__ tgt, float* __restrict__ out,
    unsigned* __restrict__ ws, int n)
{
    const int m    = blockIdx.y;                              // 0..5 (uniform)
    const int row  = blockIdx.x * blockDim.x + threadIdx.x;
    const int lane = threadIdx.x & 63;

    // uniform select (avoids scratch for a runtime-indexed pointer array)
    const float* __restrict__ mat =
        (m == 0) ? o1 : (m == 1) ? o2 : (m == 2) ? o3 :
        (m == 3) ? o4 : (m == 4) ? o5 : mimic;

    // int32-vs-int64 target layout detection (wave-uniform, self-contained).
    // int64 little-endian nonneg => odd 32-bit words all zero.
    const int idx   = 2 * lane + 1;
    const int probe = (idx < n) ? tgt[idx] : 0;
    const unsigned long long nz = __ballot(probe != 0);
    const int tstride = (nz == 0ull) ? 2 : 1;

    float gmax = -INFINITY;   // this thread's row max (matrices 0..4 only)

    if (row < n) {
        const size_t rowoff = (size_t)row * C;
        const float4* __restrict__ p4 = (const float4*)(mat + rowoff);
        // two independent top-2 trackers (halve the fmax dependence chain)
        float m1a = -INFINITY, m2a = -INFINITY;
        float m1b = -INFINITY, m2b = -INFINITY;
        #pragma unroll
        for (int i = 0; i < C / 4; ++i) {
            float4 v = p4[i];
            m2a = fmaxf(m2a, fminf(m1a, v.x)); m1a = fmaxf(m1a, v.x);
            m2b = fmaxf(m2b, fminf(m1b, v.y)); m1b = fmaxf(m1b, v.y);
            m2a = fmaxf(m2a, fminf(m1a, v.z)); m1a = fmaxf(m1a, v.z);
            m2b = fmaxf(m2b, fminf(m1b, v.w)); m1b = fmaxf(m1b, v.w);
        }
        const float m1 = fmaxf(m1a, m1b);
        const float m2 = fmaxf(fminf(m1a, m1b), fmaxf(m2a, m2b));
        const int   t  = tgt[(size_t)row * tstride];   // 0..99
        const float tv = mat[rowoff + t];              // L1-hit (row just read)
        out[1 + (size_t)row * 6 + m] = (tv == m1) ? (m1 - m2) * INV_TEMP : 0.0f;
        if (m < 5) gmax = m1;                          // mimic excluded
    }

    if (m < 5) {   // wave-uniform branch; mimic blocks skip the atomic
        #pragma unroll
        for (int s = 1; s < 64; s <<= 1) gmax = fmaxf(gmax, __shfl_xor(gmax, s));
        if (lane == 0) atomicMax(ws, enc_f(gmax));
    }
}

// In-place 6-wide softmax over out[1+row*6 .. +5]; thread 0 decodes out[0].
__global__ __launch_bounds__(256) void softmax_kernel(
    float* __restrict__ out, const unsigned* __restrict__ ws, int n)
{
    const int row = blockIdx.x * blockDim.x + threadIdx.x;
    if (row < n) {
        float* p = out + 1 + (size_t)row * 6;
        float mrg[6];
        #pragma unroll
        for (int j = 0; j < 6; ++j) mrg[j] = p[j];
        float mx = mrg[0];
        #pragma unroll
        for (int j = 1; j < 6; ++j) mx = fmaxf(mx, mrg[j]);
        float e[6], s = 0.0f;
        #pragma unroll
        for (int j = 0; j < 6; ++j) { e[j] = __expf(mrg[j] - mx); s += e[j]; }
        const float inv = 1.0f / s;
        #pragma unroll
        for (int j = 0; j < 6; ++j) p[j] = e[j] * inv;
    }
    if (row == 0) {
        unsigned e = ws[0];
        unsigned bits = (e & 0x80000000u) ? (e & 0x7FFFFFFFu) : ~e;
        out[0] = __uint_as_float(bits);
    }
}

extern "C" void kernel_launch(void* const* d_in, const int* in_sizes, int n_in,
                              void* d_out, int out_size, void* d_ws, size_t ws_size,
                              hipStream_t stream) {
    const float* o1    = (const float*)d_in[0];
    const float* o2    = (const float*)d_in[1];
    const float* o3    = (const float*)d_in[2];
    const float* o4    = (const float*)d_in[3];
    const float* o5    = (const float*)d_in[4];
    const float* mimic = (const float*)d_in[5];
    const int*   tgt   = (const int*)d_in[6];
    float*       out   = (float*)d_out;
    unsigned*    ws    = (unsigned*)d_ws;

    const int n = in_sizes[6];   // N = 65536

    setup_kernel<<<1, 1, 0, stream>>>(ws);
    dim3 grid((n + 255) / 256, 6);   // 1536 blocks -> ~24 waves/CU
    margin_kernel<<<grid, 256, 0, stream>>>(o1, o2, o3, o4, o5, mimic,
                                            tgt, out, ws, n);
    softmax_kernel<<<(n + 255) / 256, 256, 0, stream>>>(out, ws, n);
}